// Round 1
// 3233.351 us; speedup vs baseline: 1.1327x; 1.1327x over previous
//
#include <hip/hip_runtime.h>
#include <hip/hip_bf16.h>

#define N_NODE 100000
#define DIM 64
#define R_EX 8
#define R_IM 4
#define E_EX 2000000
#define E_IM 1000000
#define ND (N_NODE * DIM)

typedef __hip_bfloat16 bf16;

__device__ __forceinline__ float b2f(bf16 v) { return __bfloat162float(v); }

// dtype-agnostic load: f32 flag selects float32 vs bfloat16 interpretation
__device__ __forceinline__ float ldv(const void* p, long long i, int f32) {
    return f32 ? ((const float*)p)[i] : b2f(((const bf16*)p)[i]);
}

// ---------------- dtype detection ----------------
__global__ void detect_kernel(const void* probe, int* flag) {
    int t = threadIdx.x;
    float v = b2f(((const bf16*)probe)[t]);
    int bad = !(fabsf(v) <= 4.0f);  // catches big, inf, nan
    unsigned long long m = __ballot(bad);
    if (t == 0) *flag = (m != 0ull) ? 1 : 0;
}

// ---------------- counts ----------------
__global__ void count_kernel(const int* __restrict__ eidx, const int* __restrict__ etype,
                             float* __restrict__ cnt, int E) {
    int e = blockIdx.x * blockDim.x + threadIdx.x;
    if (e >= E) return;
    int dst = eidx[E + e];
    int r = etype[e];
    atomicAdd(&cnt[r * N_NODE + dst], 1.0f);
}

__global__ void inv_kernel(float* __restrict__ cnt, int n) {
    int i = blockIdx.x * blockDim.x + threadIdx.x;
    if (i >= n) return;
    cnt[i] = 1.0f / fmaxf(cnt[i], 1.0f);
}

// ---------------- layer 1 ----------------
__global__ void l1_init(const void* __restrict__ root, const void* __restrict__ bias,
                        const int* __restrict__ fp, float* __restrict__ x1) {
    int i = blockIdx.x * blockDim.x + threadIdx.x;
    if (i >= ND) return;
    int f32 = *fp;
    x1[i] = ldv(root, i, f32) + ldv(bias, i & (DIM - 1), f32);
}

// one 64-lane group per edge; lane d handles dim d
__global__ void l1_edge(const int* __restrict__ eidx, const int* __restrict__ etype,
                        const void* __restrict__ W1, const float* __restrict__ inv,
                        const int* __restrict__ fp, float* __restrict__ x1, int E) {
    int gid = blockIdx.x * blockDim.x + threadIdx.x;
    int e = gid >> 6;
    int d = gid & 63;
    if (e >= E) return;
    int f32 = *fp;
    int src = eidx[e];
    int dst = eidx[E + e];
    int r = etype[e];
    float w = inv[r * N_NODE + dst];
    float v = ldv(W1, ((long long)r * N_NODE + src) * DIM + d, f32);
    atomicAdd(&x1[dst * DIM + d], v * w);
}

// ---------------- attitu ----------------
__global__ void attitu_kernel(const float* __restrict__ ex1, const float* __restrict__ im1,
                              const void* __restrict__ w11, const void* __restrict__ b11,
                              const void* __restrict__ w12, const void* __restrict__ b12,
                              const void* __restrict__ w21, const void* __restrict__ b21,
                              const void* __restrict__ w22, const void* __restrict__ b22,
                              const int* __restrict__ fp,
                              float* __restrict__ t_ex, float* __restrict__ t_im) {
    int gid = blockIdx.x * blockDim.x + threadIdx.x;
    int i = gid >> 6;
    int d = gid & 63;
    if (i >= N_NODE) return;
    int f32 = *fp;
    float e1 = ex1[i * DIM + d];
    float e2 = im1[i * DIM + d];
    float p11 = e1 * ldv(w11, d, f32);
    float p12 = e2 * ldv(w12, d, f32);
    float p21 = e1 * ldv(w21, d, f32);
    float p22 = e2 * ldv(w22, d, f32);
#pragma unroll
    for (int off = 32; off; off >>= 1) {
        p11 += __shfl_xor(p11, off);
        p12 += __shfl_xor(p12, off);
        p21 += __shfl_xor(p21, off);
        p22 += __shfl_xor(p22, off);
    }
    float a11 = p11 + ldv(b11, 0, f32);
    float a12 = p12 + ldv(b12, 0, f32);
    float a21 = p21 + ldv(b21, 0, f32);
    float a22 = p22 + ldv(b22, 0, f32);

    float m1 = fmaxf(a11, a12);
    float z11 = __expf(a11 - m1), z12 = __expf(a12 - m1);
    float i1 = 1.0f / (z11 + z12);
    float s10 = z11 * i1, s11 = z12 * i1;

    float m2 = fmaxf(a21, a22);
    float z21 = __expf(a21 - m2), z22 = __expf(a22 - m2);
    float i2 = 1.0f / (z21 + z22);
    float s20 = z21 * i2, s21 = z22 * i2;

    t_ex[i * DIM + d] = s10 * e1 + s11 * e2;
    t_im[i * DIM + d] = s20 * e1 + s21 * e2;  // f2 = s2[:,1]*e2 + s2[:,0]*e1
}

// ---------------- layer 2 ----------------
// IN-PLACE: x1 buffer becomes a2 = x1 + b2 + t @ root2 (folds the final ex1+ex2 sum)
__global__ void l2_init_fused(const float* __restrict__ t, const void* __restrict__ root2,
                              const void* __restrict__ b2, const int* __restrict__ fp,
                              float* __restrict__ x1) {
    int gid = blockIdx.x * blockDim.x + threadIdx.x;
    int i = gid >> 6;
    int d = gid & 63;
    if (i >= N_NODE) return;
    int f32 = *fp;
    float tv = t[i * DIM + d];
    float acc = ldv(b2, d, f32) + x1[i * DIM + d];
    if (f32) {
        const float* W = (const float*)root2;
#pragma unroll
        for (int k = 0; k < DIM; ++k) acc += __shfl(tv, k) * W[k * DIM + d];
    } else {
        const bf16* W = (const bf16*)root2;
#pragma unroll
        for (int k = 0; k < DIM; ++k) acc += __shfl(tv, k) * b2f(W[k * DIM + d]);
    }
    x1[i * DIM + d] = acc;
}

// Factored layer-2 edge aggregation: h_r[dst] += t[src]   (no GEMM per edge!)
// Relations chunked [r0, r0+rc) to fit workspace.
__global__ void l2_agg(const int* __restrict__ eidx, const int* __restrict__ etype,
                       const float* __restrict__ t, float* __restrict__ h,
                       int E, int r0, int rc) {
    int gid = blockIdx.x * blockDim.x + threadIdx.x;
    int e = gid >> 6;
    int d = gid & 63;
    if (e >= E) return;
    int r = etype[e] - r0;
    if ((unsigned)r >= (unsigned)rc) return;
    int src = eidx[e];
    int dst = eidx[E + e];
    atomicAdd(&h[(long long)r * ND + dst * DIM + d], t[src * DIM + d]);
}

// Dense pass: a2[i] += sum_c inv[r0+c, i] * (h_c[i] @ W2[r0+c])
// One wave per node, shfl-broadcast GEMM. 100k node-GEMMs instead of 2M edge-GEMMs.
__global__ void l2_dense(const float* __restrict__ h, const void* __restrict__ W2,
                         const float* __restrict__ inv, const int* __restrict__ fp,
                         float* __restrict__ a2, int r0, int rc) {
    int gid = blockIdx.x * blockDim.x + threadIdx.x;
    int i = gid >> 6;
    int d = gid & 63;
    if (i >= N_NODE) return;
    int f32 = *fp;
    float acc = a2[i * DIM + d];
    for (int c = 0; c < rc; ++c) {
        float hv = h[(long long)c * ND + i * DIM + d];
        float w = inv[(r0 + c) * N_NODE + i];
        float s = 0.0f;
        if (f32) {
            const float* W = (const float*)W2 + (r0 + c) * DIM * DIM;
#pragma unroll
            for (int k = 0; k < DIM; ++k) s += __shfl(hv, k) * W[k * DIM + d];
        } else {
            const bf16* W = (const bf16*)W2 + (r0 + c) * DIM * DIM;
#pragma unroll
            for (int k = 0; k < DIM; ++k) s += __shfl(hv, k) * b2f(W[k * DIM + d]);
        }
        acc += w * s;
    }
    a2[i * DIM + d] = acc;
}

// Fallback (workspace too small): original per-edge GEMM
__global__ void l2_edge(const int* __restrict__ eidx, const int* __restrict__ etype,
                        const float* __restrict__ t, const void* __restrict__ W2,
                        const float* __restrict__ inv, const int* __restrict__ fp,
                        float* __restrict__ a2, int E) {
    int gid = blockIdx.x * blockDim.x + threadIdx.x;
    int e = gid >> 6;
    int d = gid & 63;
    if (e >= E) return;
    int f32 = *fp;
    int src = eidx[e];
    int dst = eidx[E + e];
    int r = etype[e];
    float tv = t[src * DIM + d];
    float acc = 0.0f;
    if (f32) {
        const float* W = (const float*)W2 + r * DIM * DIM;
#pragma unroll
        for (int k = 0; k < DIM; ++k) acc += __shfl(tv, k) * W[k * DIM + d];
    } else {
        const bf16* W = (const bf16*)W2 + r * DIM * DIM;
#pragma unroll
        for (int k = 0; k < DIM; ++k) acc += __shfl(tv, k) * b2f(W[k * DIM + d]);
    }
    float w = inv[r * N_NODE + dst];
    atomicAdd(&a2[dst * DIM + d], acc * w);
}

// ---------------- final head ----------------
__global__ void final_kernel(const float* __restrict__ a2ex, const float* __restrict__ a2im,
                             const void* __restrict__ aggW1, const void* __restrict__ aggb1,
                             const void* __restrict__ aggW2, const void* __restrict__ aggb2,
                             const int* __restrict__ fp, void* __restrict__ out) {
    int gid = blockIdx.x * blockDim.x + threadIdx.x;
    int i = gid >> 6;
    int d = gid & 63;
    if (i >= N_NODE) return;
    int f32 = *fp;
    float cex = a2ex[i * DIM + d];
    float cim = a2im[i * DIM + d];
    float h = ldv(aggb1, d, f32);
    if (f32) {
        const float* W = (const float*)aggW1;
#pragma unroll
        for (int k = 0; k < DIM; ++k) {
            h += __shfl(cex, k) * W[k * DIM + d];
            h += __shfl(cim, k) * W[(DIM + k) * DIM + d];
        }
    } else {
        const bf16* W = (const bf16*)aggW1;
#pragma unroll
        for (int k = 0; k < DIM; ++k) {
            h += __shfl(cex, k) * b2f(W[k * DIM + d]);
            h += __shfl(cim, k) * b2f(W[(DIM + k) * DIM + d]);
        }
    }
    h = (h > 0.0f) ? h : 0.01f * h;
    float o = ldv(aggb2, d, f32);
    if (f32) {
        const float* W = (const float*)aggW2;
#pragma unroll
        for (int k = 0; k < DIM; ++k) o += __shfl(h, k) * W[k * DIM + d];
        ((float*)out)[i * DIM + d] = o;
    } else {
        const bf16* W = (const bf16*)aggW2;
#pragma unroll
        for (int k = 0; k < DIM; ++k) o += __shfl(h, k) * b2f(W[k * DIM + d]);
        ((bf16*)out)[i * DIM + d] = __float2bfloat16(o);
    }
}

extern "C" void kernel_launch(void* const* d_in, const int* in_sizes, int n_in,
                              void* d_out, int out_size, void* d_ws, size_t ws_size,
                              hipStream_t stream) {
    const int* eidx_ex  = (const int*)d_in[0];
    const int* etype_ex = (const int*)d_in[1];
    const int* eidx_im  = (const int*)d_in[2];
    const int* etype_im = (const int*)d_in[3];
    const void* W1_ex   = d_in[4];
    const void* root1_ex= d_in[5];
    const void* b1_ex   = d_in[6];
    const void* W1_im   = d_in[7];
    const void* root1_im= d_in[8];
    const void* b1_im   = d_in[9];
    const void* W2_ex   = d_in[10];
    const void* root2_ex= d_in[11];
    const void* b2_ex   = d_in[12];
    const void* W2_im   = d_in[13];
    const void* root2_im= d_in[14];
    const void* b2_im   = d_in[15];
    const void* att_w11 = d_in[16];
    const void* att_b11 = d_in[17];
    const void* att_w12 = d_in[18];
    const void* att_b12 = d_in[19];
    const void* att_w21 = d_in[20];
    const void* att_b21 = d_in[21];
    const void* att_w22 = d_in[22];
    const void* att_b22 = d_in[23];
    const void* agg_W1  = d_in[24];
    const void* agg_b1  = d_in[25];
    const void* agg_W2  = d_in[26];
    const void* agg_b2  = d_in[27];

    // workspace layout (floats):
    // [flag pad 64][inv 1.2M][x1ex 6.4M][x1im 6.4M][t_ex 6.4M][t_im 6.4M][h: C*6.4M]
    float* ws = (float*)d_ws;
    int*   flag   = (int*)d_ws;
    float* inv_ex = ws + 64;
    float* inv_im = inv_ex + R_EX * N_NODE;
    float* x1ex   = inv_im + R_IM * N_NODE;   // becomes a2ex in-place
    float* x1im   = x1ex + ND;                // becomes a2im in-place
    float* t_ex   = x1im + ND;
    float* t_im   = t_ex + ND;
    float* hbuf   = t_im + ND;

    const long long base_floats = 64 + (long long)(R_EX + R_IM) * N_NODE + 4LL * ND;
    long long avail = (long long)(ws_size / sizeof(float)) - base_floats;
    int cmax = (avail > 0) ? (int)(avail / ND) : 0;
    if (cmax > R_EX) cmax = R_EX;

    const int B = 256;

    detect_kernel<<<1, 64, 0, stream>>>(b1_ex, flag);

    // counts -> inverse means
    hipMemsetAsync(inv_ex, 0, (size_t)(R_EX + R_IM) * N_NODE * sizeof(float), stream);
    count_kernel<<<(E_EX + B - 1) / B, B, 0, stream>>>(eidx_ex, etype_ex, inv_ex, E_EX);
    count_kernel<<<(E_IM + B - 1) / B, B, 0, stream>>>(eidx_im, etype_im, inv_im, E_IM);
    inv_kernel<<<((R_EX + R_IM) * N_NODE + B - 1) / B, B, 0, stream>>>(inv_ex, (R_EX + R_IM) * N_NODE);

    // layer-1
    l1_init<<<(ND + B - 1) / B, B, 0, stream>>>(root1_ex, b1_ex, flag, x1ex);
    l1_init<<<(ND + B - 1) / B, B, 0, stream>>>(root1_im, b1_im, flag, x1im);
    l1_edge<<<(E_EX * 64) / B, B, 0, stream>>>(eidx_ex, etype_ex, W1_ex, inv_ex, flag, x1ex, E_EX);
    l1_edge<<<(E_IM * 64) / B, B, 0, stream>>>(eidx_im, etype_im, W1_im, inv_im, flag, x1im, E_IM);

    // attitu fusion
    attitu_kernel<<<(N_NODE * 64 + B - 1) / B, B, 0, stream>>>(
        x1ex, x1im, att_w11, att_b11, att_w12, att_b12, att_w21, att_b21, att_w22, att_b22,
        flag, t_ex, t_im);

    // layer-2 (x1 buffers become a2 in place, with x1 folded in for the final cat-sum)
    l2_init_fused<<<(N_NODE * 64 + B - 1) / B, B, 0, stream>>>(t_ex, root2_ex, b2_ex, flag, x1ex);
    l2_init_fused<<<(N_NODE * 64 + B - 1) / B, B, 0, stream>>>(t_im, root2_im, b2_im, flag, x1im);

    if (cmax >= 1) {
        // Factored path: per-relation aggregation + dense node GEMM.
        for (int r0 = 0; r0 < R_EX; r0 += cmax) {
            int rc = (R_EX - r0 < cmax) ? (R_EX - r0) : cmax;
            hipMemsetAsync(hbuf, 0, (size_t)rc * ND * sizeof(float), stream);
            l2_agg<<<(E_EX * 64) / B, B, 0, stream>>>(eidx_ex, etype_ex, t_ex, hbuf, E_EX, r0, rc);
            l2_dense<<<(N_NODE * 64 + B - 1) / B, B, 0, stream>>>(hbuf, W2_ex, inv_ex, flag, x1ex, r0, rc);
        }
        for (int r0 = 0; r0 < R_IM; r0 += cmax) {
            int rc = (R_IM - r0 < cmax) ? (R_IM - r0) : cmax;
            hipMemsetAsync(hbuf, 0, (size_t)rc * ND * sizeof(float), stream);
            l2_agg<<<(E_IM * 64) / B, B, 0, stream>>>(eidx_im, etype_im, t_im, hbuf, E_IM, r0, rc);
            l2_dense<<<(N_NODE * 64 + B - 1) / B, B, 0, stream>>>(hbuf, W2_im, inv_im, flag, x1im, r0, rc);
        }
    } else {
        // Fallback: original per-edge GEMM
        l2_edge<<<(E_EX * 64) / B, B, 0, stream>>>(eidx_ex, etype_ex, t_ex, W2_ex, inv_ex, flag, x1ex, E_EX);
        l2_edge<<<(E_IM * 64) / B, B, 0, stream>>>(eidx_im, etype_im, t_im, W2_im, inv_im, flag, x1im, E_IM);
    }

    // fused MLP head
    final_kernel<<<(N_NODE * 64 + B - 1) / B, B, 0, stream>>>(
        x1ex, x1im, agg_W1, agg_b1, agg_W2, agg_b2, flag, (void*)d_out);
}